// Round 9
// baseline (515706.689 us; speedup 1.0000x reference)
//
#include <hip/hip_runtime.h>
#include <math.h>

#define SEQ   8192
#define NIN   256
#define H     2048
#define NBLK  128
#define NTHR  512

typedef unsigned long long u64;

// ---- ws layout (bytes from d_ws) ----
// 0     : float hA[2][H]          (16 KB) fp32 h transport, ping-pong
// 16384 : unsigned tags[2][NBLK]  (1 KB)  tag[slot][b] = step count of record
//
// ENDPOINT-REDUCED round-0 design: 128 blocks x 8 waves (was 256 x 4).
// Volume model (fits R0/R1/R3/R4/R8): step time ~ aggregate line-requests
// at the coherence point; ws is fine-grained (uncached) so caching tricks
// are void (R8: FETCH unchanged). Halving endpoints cuts requests/step
// ~64K -> ~20K: h-fetch 32K->16K, tags 8 lines (poll 4K->1K/round),
// publish 2K->128 (16 floats = ONE 64B line per block).
// Transport semantics byte-identical to round-0 (sc1 relaxed, ping-pong).

__global__ void lstm_init(const float* __restrict__ h0, float* __restrict__ ws)
{
    const int j = threadIdx.x;   // one block of 512
    unsigned* tags = (unsigned*)(ws + 2 * H);
    #pragma unroll
    for (int r = 0; r < 4; ++r) ws[4 * j + r] = h0[4 * j + r];
    if (j < NBLK) {
        tags[j]        = 0u;           // slot 0 carries h_0 with tag 0
        tags[NBLK + j] = 0xFFFFFFFFu;  // slot 1 not ready
    }
}

// Wave-0-only poll: lane ln checks one packed tag pair (u64 = 2 tags) until
// all 128 tags == t. Relaxed sc1 loads, no fences. 8 line-reqs per round.
__device__ __forceinline__ void wave_poll_tags(const u64* tp, unsigned t, int ln)
{
    const u64 want = ((u64)t << 32) | (u64)t;
    for (;;) {
        u64 a = __hip_atomic_load(tp + ln, __ATOMIC_RELAXED, __HIP_MEMORY_SCOPE_AGENT);
        if (__all(a == want)) break;
        __builtin_amdgcn_s_sleep(2);
    }
}

// Persistent LSTM. fp32 weights register-resident, fp64 recurrence math,
// fp32 h transport. Block b owns h[16b..16b+16); wave wv (0..7) computes
// gate (wv>>1), j-half (wv&1): rows R = (wv>>1)*H + 16b + (wv&1)*8 + r.
// Lane ln holds w_hh[R][32ln..32ln+32) for its 8 rows.
__global__ void __launch_bounds__(NTHR, 1)
lstm_persist(const float* __restrict__ x, const float* __restrict__ c0,
             const float* __restrict__ w_ih, const float* __restrict__ w_hh,
             const float* __restrict__ b_ih, const float* __restrict__ b_hh,
             const float* __restrict__ w_lin, const float* __restrict__ b_lin,
             float* __restrict__ out, float* __restrict__ ws)
{
    const int b = blockIdx.x, tid = threadIdx.x;
    const int wv = tid >> 6, ln = tid & 63;
    float*     hA    = ws;
    unsigned*  tags  = (unsigned*)(ws + 2 * H);
    const u64* tagsU = (const u64*)tags;

    __shared__ float  h_lds[H + H / 32];   // stride-33 padding
    __shared__ double gsum[8][8];
    __shared__ double bias_s[8][8];
    __shared__ double red0[8], red1[8];

    if (tid < 64) {
        // row R for (wave tid>>3, r tid&7): (tid>>4)*H + 16b + (tid&15)
        int R = (tid >> 4) * H + b * 16 + (tid & 15);
        bias_s[tid >> 3][tid & 7] = (double)b_ih[R] + (double)b_hh[R];
    }
    // cell state: wave-0 lanes 0-15 own c[16b+ln]
    double c_reg = (wv == 0 && ln < 16) ? (double)c0[b * 16 + ln] : 0.0;

    float wreg[8][32];
    float wih[8][4];
    {
        const int g = wv >> 1, half = wv & 1;
        #pragma unroll
        for (int r = 0; r < 8; ++r) {
            const int R = g * H + b * 16 + half * 8 + r;
            const float4* wp = (const float4*)(w_hh + (size_t)R * H + ln * 32);
            #pragma unroll
            for (int q = 0; q < 8; ++q) ((float4*)wreg[r])[q] = wp[q];
            *(float4*)wih[r] = *(const float4*)(w_ih + (size_t)R * NIN + ln * 4);
        }
    }
    __syncthreads();

    float4 xr = *(const float4*)(x + ln * 4);
    float4 xn = xr;

    for (int t = 0; t < SEQ; ++t) {
        const int slot = t & 1;

        // x prefetch before the poll: latency hides under the wait
        if (t + 1 < SEQ) xn = *(const float4*)(x + (size_t)(t + 1) * NIN + ln * 4);

        if (wv == 0) wave_poll_tags(tagsU + slot * (NBLK / 2), (unsigned)t, ln);
        __syncthreads();   // #1: all 128 records of step t are at coherence point

        // fetch h: thread tid owns floats [4*tid, 4*tid+4) -> padded LDS
        {
            const u64* hp = (const u64*)(hA + slot * H) + tid * 2;
            const int base = 4 * tid + (tid >> 3);
            #pragma unroll
            for (int q = 0; q < 2; ++q) {
                u64 v = __hip_atomic_load(hp + q, __ATOMIC_RELAXED, __HIP_MEMORY_SCOPE_AGENT);
                union { u64 u; float2 f; } cv; cv.u = v;
                h_lds[base + 2 * q]     = cv.f.x;
                h_lds[base + 2 * q + 1] = cv.f.y;
            }
        }
        __syncthreads();   // #2

        // matvec: fp32 w x fp32 h, fp64 accumulate
        float hbuf[32];
        {
            const float* hp = &h_lds[33 * ln];
            #pragma unroll
            for (int q = 0; q < 32; ++q) hbuf[q] = hp[q];
        }
        double acc[8];
        #pragma unroll
        for (int r = 0; r < 8; ++r)
            acc[r] = (double)wih[r][0] * (double)xr.x + (double)wih[r][1] * (double)xr.y
                   + (double)wih[r][2] * (double)xr.z + (double)wih[r][3] * (double)xr.w;
        #pragma unroll
        for (int q = 0; q < 32; ++q) {
            const double hq = (double)hbuf[q];
            #pragma unroll
            for (int r = 0; r < 8; ++r)
                acc[r] = fma((double)wreg[r][q], hq, acc[r]);
        }
        #pragma unroll
        for (int off = 32; off >= 1; off >>= 1) {
            #pragma unroll
            for (int r = 0; r < 8; ++r) acc[r] += __shfl_xor(acc[r], off, 64);
        }
        if (ln == 0) {
            #pragma unroll
            for (int r = 0; r < 8; ++r) gsum[wv][r] = acc[r];
        }
        __syncthreads();   // #3

        // wave 0: activations (all 64 lanes, one row each), update, publish
        if (wv == 0) {
            // lane ln covers gate g=ln>>4, j=ln&15 -> gsum flat index ln
            double v = gsum[ln >> 3][ln & 7] + bias_s[ln >> 3][ln & 7];
            double actv = ((ln >> 4) == 2) ? tanh(v) : 1.0 / (1.0 + exp(-v));
            const int j = ln & 15;
            double ai = __shfl(actv, j,      64);
            double af = __shfl(actv, j + 16, 64);
            double ag = __shfl(actv, j + 32, 64);
            double ao = __shfl(actv, j + 48, 64);
            if (ln < 16) {
                double c = af * c_reg + ai * ag;
                c_reg = c;
                float hnew = (float)(ao * tanh(c));
                // 16 lanes store 16 consecutive floats = ONE 64B line
                unsigned* dst = (unsigned*)(hA + (1 - slot) * H) + 16 * b + ln;
                __hip_atomic_store(dst, __builtin_bit_cast(unsigned, hnew),
                                   __ATOMIC_RELAXED, __HIP_MEMORY_SCOPE_AGENT);
            }
            // order data stores before tag store (atomic->atomic: waitcnt suffices)
            asm volatile("s_waitcnt vmcnt(0)" ::: "memory");
            if (ln == 0)
                __hip_atomic_store(&tags[(1 - slot) * NBLK + b], (unsigned)(t + 1),
                                   __ATOMIC_RELAXED, __HIP_MEMORY_SCOPE_AGENT);
        }
        xr = xn;
    }

    // ---- epilogue: block 0 computes logits from h(SEQ) (slot 0, tag SEQ) ----
    if (b == 0) {
        if (wv == 0) wave_poll_tags(tagsU, (unsigned)SEQ, ln);
        __syncthreads();
        double a0 = 0., a1 = 0.;
        {
            const u64* hp = (const u64*)hA + tid * 2;
            #pragma unroll
            for (int q = 0; q < 2; ++q) {
                u64 v = __hip_atomic_load(hp + q, __ATOMIC_RELAXED, __HIP_MEMORY_SCOPE_AGENT);
                union { u64 u; float2 f; } cv; cv.u = v;
                const int k = 4 * tid + 2 * q;
                a0 = fma((double)w_lin[k],         (double)cv.f.x, a0);
                a0 = fma((double)w_lin[k + 1],     (double)cv.f.y, a0);
                a1 = fma((double)w_lin[H + k],     (double)cv.f.x, a1);
                a1 = fma((double)w_lin[H + k + 1], (double)cv.f.y, a1);
            }
        }
        #pragma unroll
        for (int off = 32; off >= 1; off >>= 1) {
            a0 += __shfl_xor(a0, off, 64);
            a1 += __shfl_xor(a1, off, 64);
        }
        if (ln == 0) { red0[wv] = a0; red1[wv] = a1; }
        __syncthreads();
        if (tid == 0) {
            double s0 = 0., s1 = 0.;
            #pragma unroll
            for (int w = 0; w < 8; ++w) { s0 += red0[w]; s1 += red1[w]; }
            out[0] = (float)(s0 + (double)b_lin[0]);
            out[1] = (float)(s1 + (double)b_lin[1]);
        }
    }
}

extern "C" void kernel_launch(void* const* d_in, const int* in_sizes, int n_in,
                              void* d_out, int out_size, void* d_ws, size_t ws_size,
                              hipStream_t stream) {
    const float* x     = (const float*)d_in[0];
    const float* h0    = (const float*)d_in[1];
    const float* c0    = (const float*)d_in[2];
    const float* w_ih  = (const float*)d_in[3];
    const float* w_hh  = (const float*)d_in[4];
    const float* b_ih  = (const float*)d_in[5];
    const float* b_hh  = (const float*)d_in[6];
    const float* w_lin = (const float*)d_in[7];
    const float* b_lin = (const float*)d_in[8];
    float* out = (float*)d_out;
    float* ws  = (float*)d_ws;

    lstm_init<<<1, NTHR, 0, stream>>>(h0, ws);
    lstm_persist<<<NBLK, NTHR, 0, stream>>>(
        x, c0, w_ih, w_hh, b_ih, b_hh, w_lin, b_lin, out, ws);
}